// Round 22
// baseline (343.044 us; speedup 1.0000x reference)
//
#include <hip/hip_runtime.h>

typedef unsigned short u16;
typedef unsigned int   u32;
typedef __attribute__((ext_vector_type(4)))  u16   us4;
typedef __attribute__((ext_vector_type(8)))  u16   us8;
typedef __attribute__((ext_vector_type(8)))  short s8v;
typedef __attribute__((ext_vector_type(16))) float f32x16;

#define L_   2048
#define D_   512
#define H_   8
#define PE_  2097152ull      // B*L*D elements of one fp32 projection array

// ---- ws layout (bytes) ----
#define MATE    2097152ull   // u16 elems per mat
#define BHE     131072u      // u16 elems per (bh) slice of a mat (2048*64)
#define VT_OFF  33554432ull
#define ORH_OFF 41943040ull
#define ORL_OFF 46137344ull
#define OIH_OFF 50331648ull
#define OIL_OFF 54525952ull
#define LV_OFF  58720256ull
#define MX0_OFF 58851328ull  // per-row max of j-half 0 (32768 f32)
#define MX1_OFF 58982400ull  // per-row max of j-half 1

// ---- d_out scratch (bytes from out base; inside attnbuf, dead before attn writes) ----
#define XRH_O 16777216ull
#define XRL_O 20971520ull
#define XIH_O 25165824ull
#define XIL_O 29360128ull
#define WSP_O 33554432ull    // W splits: 3 x (hi 512KB + lo 512KB), tile-major pre-swizzled

#define MFMA32(a,b,c) __builtin_amdgcn_mfma_f32_32x32x16_bf16(a,b,c,0,0,0)
#define ROWOF(r,hi) (((r)&3) + 8*((r)>>2) + 4*(hi))

__device__ __forceinline__ u16 f2bf(float x){
    u32 u = __float_as_uint(x);
    u += 0x7FFFu + ((u>>16)&1u);
    return (u16)(u>>16);
}
__device__ __forceinline__ float bf2f(u16 h){ return __uint_as_float(((u32)h)<<16); }

// async 16B/lane global->LDS copy (LDS dest = wave-uniform base + lane*16)
__device__ __forceinline__ void glds16(const void* gsrc, void* ldst)
{
    __builtin_amdgcn_global_load_lds(
        (const __attribute__((address_space(1))) u32*)(unsigned long long)gsrc,
        (__attribute__((address_space(3))) u32*)(u32)(unsigned long long)ldst,
        16, 0, 0);
}
// one 8KB qk-mat (64 rows x 128B contiguous, pre-swizzled): 8 x 1KB issues
__device__ __forceinline__ void glds_mat(unsigned char* Lp, u32 matOff,
                                         const u16* g, int rowBase, int lane)
{
    const char* gb = (const char*)(g + (size_t)rowBase * 64);
    #pragma unroll
    for (int s = 0; s < 8; ++s)
        glds16(gb + s*1024 + lane*16, Lp + matOff + s*1024);
}
// half a V^T mat (4 x 1KB segments; rows strided 4096B, pre-swizzled per 128B block)
__device__ __forceinline__ void glds_vt(unsigned char* Lp, u32 matOff,
                                        const u16* g, int j0, int lane, int s0)
{
    #pragma unroll
    for (int s = 0; s < 4; ++s) {
        int seg = s0 + s;
        int dh  = seg*8 + (lane >> 3);
        const char* gp = (const char*)g + (size_t)dh*4096 + (size_t)j0*2 + (lane & 7)*16;
        glds16(gp, Lp + matOff + seg*1024u);
    }
}

// ============================================================
// Prep: split wave_real / wave_imag into bf16 hi/lo mats (d_out scratch)
// ============================================================
__global__ __launch_bounds__(256)
void split_prep_kernel(const float* __restrict__ wr, const float* __restrict__ wi,
                       unsigned char* __restrict__ outb)
{
    const int z = blockIdx.y;
    const float* src = z ? wi : wr;
    u16* hg = (u16*)(outb + (z ? XIH_O : XRH_O));
    u16* lg = (u16*)(outb + (z ? XIL_O : XRL_O));
    const size_t idx4 = ((size_t)blockIdx.x * 256 + threadIdx.x) * 4;
    float4 v = *(const float4*)&src[idx4];
    float vv[4] = { v.x, v.y, v.z, v.w };
    us4 h, l;
    #pragma unroll
    for (int c = 0; c < 4; ++c) {
        u16 hb = f2bf(vv[c]);
        h[c] = hb;
        l[c] = f2bf(vv[c] - bf2f(hb));
    }
    *(us4*)&hg[idx4] = h;
    *(us4*)&lg[idx4] = l;
}

// ============================================================
// Prep: split Wq/Wk/Wv into PRE-SWIZZLED tile-major bf16 hi/lo.
// ============================================================
__global__ __launch_bounds__(256)
void wsplit_prep_kernel(const float* __restrict__ Wq, const float* __restrict__ Wk,
                        const float* __restrict__ Wv, unsigned char* __restrict__ outb)
{
    const int tileid = blockIdx.x;          // nb*8 + kb
    const int z = blockIdx.y;               // 0 Wq, 1 Wk, 2 Wv
    const float* W = (z == 0) ? Wq : (z == 1) ? Wk : Wv;
    u16* hg = (u16*)(outb + WSP_O + (size_t)z*1048576ull) + (size_t)tileid*4096;
    u16* lg = hg + 262144;                  // +512KB
    const int nb = tileid >> 3, kb = tileid & 7;
    const int t  = threadIdx.x;
    const int r  = t >> 2;
    const int c0 = (t & 3) * 16;
    const float* src = W + (size_t)(nb*64 + r)*512 + kb*64 + c0;
    #pragma unroll
    for (int j = 0; j < 2; ++j) {
        us8 hv, lv;
        #pragma unroll
        for (int e = 0; e < 8; ++e) {
            float v = src[j*8 + e];
            u16 hb = f2bf(v);
            hv[e] = hb;
            lv[e] = f2bf(v - bf2f(hb));
        }
        int dst = r*64 + ((c0 + j*8) ^ ((r & 7) << 3));
        *(us8*)(hg + dst) = hv;
        *(us8*)(lg + dst) = lv;
    }
}

// ============================================================
// LDS fragment read (XOR swizzle byte ^= (row&7)<<4)
// ============================================================
__device__ __forceinline__ s8v ldfrag(const unsigned char* Lp, u32 matOff, u32 row, u32 colb)
{
    return *(const s8v*)(Lp + matOff + row*128u + (colb ^ ((row&7u)<<4)));
}

// ============================================================
// MFMA projection: C = X @ W^T + b for 6 combos. (R19, unchanged)
// ============================================================
__global__ __launch_bounds__(256, 2)
void proj_mfma_kernel(const unsigned char* __restrict__ scr,
                      const float* __restrict__ bq, const float* __restrict__ bk,
                      const float* __restrict__ bv,
                      u16* __restrict__ qk, u16* __restrict__ vt)
{
    const int z = blockIdx.z;
    const u16* Ah_g = (const u16*)(scr + ((z & 1) ? XIH_O : XRH_O));
    const u16* Al_g = (const u16*)(scr + ((z & 1) ? XIL_O : XRL_O));
    const int wsel = z >> 1;
    const float* bias = (wsel == 0) ? bq : (wsel == 1) ? bk : bv;
    const bool four = (wsel < 2);

    const u16* wh = (const u16*)(scr + WSP_O + (size_t)wsel*1048576ull);
    const u16* wl = wh + 262144;

    const int m0 = blockIdx.x * 128;
    const int n0 = blockIdx.y * 64;
    const int nb = blockIdx.y;

    __shared__ __align__(16) unsigned char L[49152];
    enum : u32 { AH=0, AL=16384, BH=32768, BL=40960 };

    const int tid  = threadIdx.x;
    const int lane = tid & 63;
    const int wid  = tid >> 6;
    const int wr   = wid >> 1, wc = wid & 1;
    const int l31  = lane & 31;
    const int hi   = lane >> 5;
    const u32 rowA0 = (u32)(wr*64 + l31);
    const u32 rowB  = (u32)(wc*32 + l31);

    f32x16 c0, c1;
    #pragma unroll
    for (int r = 0; r < 16; ++r) { c0[r] = 0.f; c1[r] = 0.f; }

    const int ch = tid & 7, r0 = tid >> 3;

    for (int k0 = 0; k0 < 512; k0 += 64) {
        __syncthreads();
        {
            const int kb = k0 >> 6;
            const size_t toff = (size_t)(nb*8 + kb)*4096;
            if (wid == 0)              glds_mat(L, BH, wh + toff, 0, lane);
            else if (wid == 1 && four) glds_mat(L, BL, wl + toff, 0, lane);
        }
        #pragma unroll
        for (int rr = 0; rr < 4; ++rr) {
            u32 row = (u32)(rr*32 + r0);
            u32 dst = row*128u + (((u32)ch<<4) ^ ((row&7u)<<4));
            us8 vh = *(const us8*)(Ah_g + (size_t)(m0 + row)*512 + k0 + ch*8);
            *(us8*)(L + AH + dst) = vh;
            if (four) {
                us8 vl = *(const us8*)(Al_g + (size_t)(m0 + row)*512 + k0 + ch*8);
                *(us8*)(L + AL + dst) = vl;
            }
        }
        __syncthreads();

        #pragma unroll
        for (int ks = 0; ks < 4; ++ks) {
            u32 colb = (u32)(ks*32 + hi*16);
            s8v a0h = ldfrag(L, AH, rowA0,      colb);
            s8v a1h = ldfrag(L, AH, rowA0 + 32, colb);
            s8v bh_ = ldfrag(L, BH, rowB,       colb);
            c0 = MFMA32(a0h, bh_, c0);
            c1 = MFMA32(a1h, bh_, c1);
            if (four) {
                s8v a0l = ldfrag(L, AL, rowA0,      colb);
                s8v a1l = ldfrag(L, AL, rowA0 + 32, colb);
                s8v bl_ = ldfrag(L, BL, rowB,       colb);
                c0 = MFMA32(a0h, bl_, c0); c0 = MFMA32(a0l, bh_, c0); c0 = MFMA32(a0l, bl_, c0);
                c1 = MFMA32(a1h, bl_, c1); c1 = MFMA32(a1l, bh_, c1); c1 = MFMA32(a1l, bl_, c1);
            }
        }
    }

    const int n  = n0 + wc*32 + l31;
    const float bvv = bias[n];
    const int h  = n >> 6, dh = n & 63;

    if (z < 4) {
        u16* hg = qk + (size_t)(2*z)   * MATE;
        u16* lg = qk + (size_t)(2*z+1) * MATE;
        #pragma unroll
        for (int f = 0; f < 2; ++f) {
            const f32x16& c = f ? c1 : c0;
            #pragma unroll
            for (int r = 0; r < 16; ++r) {
                int m  = m0 + wr*64 + 32*f + ROWOF(r, hi);
                int b_ = m >> 11, i = m & 2047;
                size_t idx = (size_t)(b_*8 + h)*BHE + (size_t)i*64 + (dh ^ ((i&7)<<3));
                float v = c[r] + bvv;
                u16 hb = f2bf(v);
                hg[idx] = hb;
                lg[idx] = f2bf(v - bf2f(hb));
            }
        }
    } else {
        u16* vg = vt + (size_t)(z & 1) * MATE;
        #pragma unroll
        for (int f = 0; f < 2; ++f) {
            const f32x16& c = f ? c1 : c0;
            #pragma unroll
            for (int g = 0; g < 4; ++g) {
                int mb = m0 + wr*64 + 32*f + 8*g + 4*hi;
                int b_ = mb >> 11, ib = mb & 2047;
                us4 pv;
                #pragma unroll
                for (int j = 0; j < 4; ++j) pv[j] = f2bf(c[4*g + j] + bvv);
                int ibs = ib ^ ((dh & 7) << 3);
                *(us4*)&vg[(size_t)(b_*8 + h)*BHE + (size_t)dh*2048 + ibs] = pv;
            }
        }
    }
}

// ============================================================
// QK row-max kernel (sweep-1 split out, j-halved). Grid 1024:
// bid -> xcd=bid&7, seq=bid>>3; bh=2*xcd+(seq>>6), rem=seq&63,
// it=rem>>1, jh=rem&1. LDS 48KB -> 3 blocks/CU. Math identical
// to the old in-situ sweep1 (hi*hi QK, 2 tiles/barrier-pair).
// ============================================================
__global__ __launch_bounds__(256, 2)
void qkmax_kernel(const u16* __restrict__ qk,
                  float* __restrict__ mx0, float* __restrict__ mx1)
{
    const int bid = blockIdx.x;
    const int xcd = bid & 7;
    const int seq = bid >> 3;
    const int bh  = xcd*2 + (seq >> 6);
    const int rem = seq & 63;
    const int i0  = (rem >> 1) * 64;
    const int jh  = rem & 1;
    const int jbase = jh * 16;
    const int tid  = threadIdx.x;
    const int lane = tid & 63;
    const int wid  = tid >> 6;
    const int wr   = wid >> 1, wc = wid & 1;
    const int l31  = lane & 31;
    const int hi   = lane >> 5;
    const u32 rowA = wr*32 + l31;
    const u32 rowB = wc*32 + l31;

    __shared__ __align__(16) unsigned char L[49152];
    enum : u32 { QRH=0, QIH=8192, KB0=16384 };   // 4 K slots 16K..48K
    float* sc = (float*)(L + KB0);

    const u16* qrh = qk + 0*MATE + (size_t)bh*BHE;
    const u16* qih = qk + 2*MATE + (size_t)bh*BHE;
    const u16* krh = qk + 4*MATE + (size_t)bh*BHE;
    const u16* kih = qk + 6*MATE + (size_t)bh*BHE;

    // stage Q-hi (waves 0,1)
    if (wid == 0)      glds_mat(L, QRH, qrh, i0, lane);
    else if (wid == 1) glds_mat(L, QIH, qih, i0, lane);

    float mxv[16];
    #pragma unroll
    for (int r = 0; r < 16; ++r) mxv[r] = 0.f;

    const u16* s1src = (wid & 1) ? kih : krh;
    const u32  s1off = KB0 + (u32)wid * 8192u;

    for (int jp = 0; jp < 8; ++jp) {
        __syncthreads();                       // prev reads done (drains Q at jp=0)
        glds_mat(L, s1off, s1src, (jbase + 2*jp + (wid >> 1))*64, lane);
        __syncthreads();                       // K visible (vmcnt drained)
        __builtin_amdgcn_s_setprio(1);
        #pragma unroll
        for (int half = 0; half < 2; ++half) {
            const u32 kR = KB0 + (half ? 16384u : 0u);
            const u32 kI = kR + 8192u;
            f32x16 ir, ip, in_;
            #pragma unroll
            for (int r = 0; r < 16; ++r) { ir[r]=0.f; ip[r]=0.f; in_[r]=0.f; }
            #pragma unroll
            for (int ks = 0; ks < 4; ++ks) {
                u32 colb = ks*32 + hi*16;
                s8v aR = ldfrag(L, QRH, rowA, colb);
                s8v aI = ldfrag(L, QIH, rowA, colb);
                s8v bR = ldfrag(L, kR,  rowB, colb);
                s8v bI = ldfrag(L, kI,  rowB, colb);
                ir  = MFMA32(aR, bR, ir);
                ir  = MFMA32(aI, bI, ir);
                ip  = MFMA32(aR, bI, ip);
                in_ = MFMA32(aI, bR, in_);
            }
            #pragma unroll
            for (int r = 0; r < 16; ++r) {
                float xr = ir[r], xi = ip[r] - in_[r];
                float q = xr*xr + xi*xi;
                mxv[r] = fmaxf(mxv[r], q * 0.125f);
            }
        }
        __builtin_amdgcn_s_setprio(0);
    }
    #pragma unroll
    for (int m = 1; m < 32; m <<= 1)
        #pragma unroll
        for (int r = 0; r < 16; ++r) mxv[r] = fmaxf(mxv[r], __shfl_xor(mxv[r], m));

    __syncthreads();                           // last K reads done -> sc free
    #pragma unroll
    for (int r = 0; r < 16; ++r)
        if (l31 == r) sc[wc*64 + wr*32 + ROWOF(r,hi)] = mxv[r];
    __syncthreads();

    if (tid < 64) {
        float* gout = (jh ? mx1 : mx0) + (size_t)bh*2048 + i0;
        gout[tid] = fmaxf(sc[tid], sc[64 + tid]);
    }
}

// ============================================================
// MFMA attention — champion sweep-2 only (4 barriers/jt, V/P overlay
// K, bf16 e into first half of each attention row); row max loaded
// from the qkmax kernel's mx0/mx1. XCD-chunked grid (R21).
// ============================================================
__global__ __launch_bounds__(256, 2)
void attn_mfma_kernel(const u16* __restrict__ qk,
                      const u16* __restrict__ vt,
                      float* __restrict__ attnbuf,
                      u16* __restrict__ orh, u16* __restrict__ orl,
                      u16* __restrict__ oih, u16* __restrict__ oil,
                      float* __restrict__ l_out,
                      const float* __restrict__ mx0, const float* __restrict__ mx1)
{
    const int bid = blockIdx.x;
    const int xcd = bid & 7;
    const int seq = bid >> 3;
    const int bh  = xcd*2 + (seq >> 5);
    const int i0  = (seq & 31) * 64;
    const int tid  = threadIdx.x;
    const int lane = tid & 63;
    const int wid  = tid >> 6;
    const int wr   = wid >> 1, wc = wid & 1;
    const int l31  = lane & 31;
    const int hi   = lane >> 5;
    const u32 rowA = wr*32 + l31;
    const u32 rowB = wc*32 + l31;

    __shared__ __align__(16) unsigned char L[49152];
    enum : u32 { QRH=0, QIH=8192,
                 KRH=16384, KRL=24576, KIH=32768, KIL=40960,
                 VRo=16384, VIo=24576,          // overlay KRH,KRL
                 PAC=32768, PAS=40960 };        // overlay KIH,KIL
    float* sc = (float*)(L + PAC);

    const u16* qrh = qk + 0*MATE + (size_t)bh*BHE;
    const u16* qrl = qk + 1*MATE + (size_t)bh*BHE;
    const u16* qih = qk + 2*MATE + (size_t)bh*BHE;
    const u16* qil = qk + 3*MATE + (size_t)bh*BHE;
    const u16* krh = qk + 4*MATE + (size_t)bh*BHE;
    const u16* krl = qk + 5*MATE + (size_t)bh*BHE;
    const u16* kih = qk + 6*MATE + (size_t)bh*BHE;
    const u16* kil = qk + 7*MATE + (size_t)bh*BHE;
    const u16* vtr = vt + 0*MATE + (size_t)bh*BHE;
    const u16* vti = vt + 1*MATE + (size_t)bh*BHE;

    // ---- prologue: wave w stages one Q mat; lo mats land in K temp slots ----
    {
        const u16* qsrc = (wid == 0) ? qrh : (wid == 1) ? qih : (wid == 2) ? qrl : qil;
        const u32  qdst = (wid == 0) ? QRH : (wid == 1) ? QIH : (wid == 2) ? KRH : KRL;
        glds_mat(L, qdst, qsrc, i0, lane);
    }
    __syncthreads();
    // lift Q-lo fragments to registers (32 VGPR)
    s8v qfl[2][4];
    #pragma unroll
    for (int ks = 0; ks < 4; ++ks) {
        u32 colb = (u32)(ks*32 + hi*16);
        qfl[0][ks] = ldfrag(L, KRH, rowA, colb);   // QRL
        qfl[1][ks] = ldfrag(L, KRL, rowA, colb);   // QIL
    }

    // row maxes from qkmax kernel (L2-hot, 32 scalar loads/thread)
    const float* m0b = mx0 + (size_t)bh*2048 + i0;
    const float* m1b = mx1 + (size_t)bh*2048 + i0;
    float mfin[16];
    #pragma unroll
    for (int r = 0; r < 16; ++r) {
        u32 row = wr*32 + ROWOF(r,hi);
        mfin[r] = fmaxf(m0b[row], m1b[row]);
    }

    // ---------------- sweep 2 (4 barriers/jt, V/P overlay K) ----------------
    f32x16 ore, oim;
    float lp[16];
    #pragma unroll
    for (int r = 0; r < 16; ++r) { ore[r]=0.f; oim[r]=0.f; lp[r]=0.f; }

    const u16* s2src = (wid == 0) ? krh : (wid == 1) ? krl : (wid == 2) ? kih : kil;
    const u32  s2off = 16384u + (u32)wid * 8192u;
    const u16* vsrc  = (wid < 2) ? vtr : vti;
    const u32  voff  = (wid < 2) ? VRo : VIo;
    const int  vseg  = (wid & 1) * 4;

    // bf16 e destination: first half (4KB) of each 8KB attention row
    u16* ebase = (u16*)(attnbuf + (size_t)bh*4194304ull + (size_t)i0*2048);

    for (int jt = 0; jt < 32; ++jt) {
        const int j0 = jt * 64;
        __syncthreads();                       // #1: PV(jt-1) done; K region free (fences qfl lift at jt=0)
        glds_mat(L, s2off, s2src, j0, lane);   // wave w -> K mat w
        __syncthreads();                       // #2: K staged (vmcnt drained)

        f32x16 ir, ip, in_;
        #pragma unroll
        for (int r = 0; r < 16; ++r) { ir[r]=0.f; ip[r]=0.f; in_[r]=0.f; }
        __builtin_amdgcn_s_setprio(1);
        #pragma unroll
        for (int ks = 0; ks < 4; ++ks) {
            u32 colb = ks*32 + hi*16;
            s8v aRH = ldfrag(L, QRH, rowA, colb);
            s8v aIH = ldfrag(L, QIH, rowA, colb);
            s8v aRL = qfl[0][ks];
            s8v aIL = qfl[1][ks];
            s8v bRH = ldfrag(L, KRH, rowB, colb);
            s8v bRL = ldfrag(L, KRL, rowB, colb);
            s8v bIH = ldfrag(L, KIH, rowB, colb);
            s8v bIL = ldfrag(L, KIL, rowB, colb);
            ir = MFMA32(aRH, bRH, ir); ir = MFMA32(aRH, bRL, ir); ir = MFMA32(aRL, bRH, ir);
            ir = MFMA32(aIH, bIH, ir); ir = MFMA32(aIH, bIL, ir); ir = MFMA32(aIL, bIH, ir);
            ip  = MFMA32(aRH, bIH, ip);  ip  = MFMA32(aRH, bIL, ip);  ip  = MFMA32(aRL, bIH, ip);
            in_ = MFMA32(aIH, bRH, in_); in_ = MFMA32(aIH, bRL, in_); in_ = MFMA32(aIL, bRH, in_);
        }
        __builtin_amdgcn_s_setprio(0);
        __syncthreads();                       // #3: K reads done -> V/P may overwrite

        glds_vt(L, voff, vsrc, j0, lane, vseg);   // async V; lands under pointwise

        // pointwise: e (bf16) -> attn row first-half; P -> LDS (hides V loads)
        #pragma unroll
        for (int r = 0; r < 16; ++r) {
            float xr = ir[r], xi = ip[r] - in_[r];
            float q  = fmaf(xr, xr, xi*xi);
            float e  = __expf(fmaf(q, 0.125f, -mfin[r]));
            lp[r] += e;
            float iv = rsqrtf(q);
            float t  = e * iv;
            float pc = (q > 0.f) ? xr*t : e;
            float ps = (q > 0.f) ? xi*t : 0.0f;
            u32 rowloc = wr*32 + ROWOF(r,hi);
            ebase[(size_t)rowloc*4096 + j0 + wc*32 + l31] = f2bf(e);
            u32 colb2 = (wc*32 + l31)*2;
            *(u16*)(L + PAC + rowloc*128u + (colb2 ^ ((rowloc&7u)<<4))) = f2bf(pc);
            *(u16*)(L + PAS + rowloc*128u + (colb2 ^ ((rowloc&7u)<<4))) = f2bf(ps);
        }
        __syncthreads();                       // #4: V (vmcnt) + P visible

        __builtin_amdgcn_s_setprio(1);
        #pragma unroll
        for (int ks = 0; ks < 4; ++ks) {
            u32 colb = ks*32 + hi*16;
            s8v aC = ldfrag(L, PAC, rowA, colb);
            s8v aS = ldfrag(L, PAS, rowA, colb);
            s8v vR = ldfrag(L, VRo, rowB, colb);
            s8v vI = ldfrag(L, VIo, rowB, colb);
            s8v vN = vI ^ (short)0x8000;       // -Vi (register sign-flip)
            ore = MFMA32(aC, vR, ore); ore = MFMA32(aS, vN, ore);
            oim = MFMA32(aS, vR, oim); oim = MFMA32(aC, vI, oim);
        }
        __builtin_amdgcn_s_setprio(0);
    }

    // ---------------- epilogue: l, normalize O, store splits ----------------
    #pragma unroll
    for (int m = 1; m < 32; m <<= 1)
        #pragma unroll
        for (int r = 0; r < 16; ++r) lp[r] += __shfl_xor(lp[r], m);

    __syncthreads();                           // last PV done -> reuse PAC scratch
    #pragma unroll
    for (int r = 0; r < 16; ++r)
        if (l31 == r) sc[wc*64 + wr*32 + ROWOF(r,hi)] = lp[r];
    __syncthreads();

    const int b_ = bh >> 3, h = bh & 7;
    const size_t cb = (size_t)h*64 + wc*32 + l31;
    #pragma unroll
    for (int r = 0; r < 16; ++r) {
        u32 row = wr*32 + ROWOF(r,hi);
        float ls = sc[row] + sc[64 + row];
        if (wc == 0 && l31 == 0) l_out[(size_t)bh*2048 + i0 + row] = ls;
        float inv = 1.0f / ls;
        size_t idx = ((size_t)b_*2048 + i0 + row)*512 + cb;
        float vr = ore[r] * inv;
        float vi = oim[r] * inv;
        u16 hr = f2bf(vr); orh[idx] = hr; orl[idx] = f2bf(vr - bf2f(hr));
        u16 hw = f2bf(vi); oih[idx] = hw; oil[idx] = f2bf(vi - bf2f(hw));
    }
}

// ============================================================
// Expand: one block per attention row. Read the row's bf16 e (first
// 4KB, into registers), sync, write the full fp32 row = e / l[row].
// ============================================================
__global__ __launch_bounds__(256)
void expand_attn_kernel(float* __restrict__ attnbuf, const float* __restrict__ l)
{
    const int row = blockIdx.x;                // bh*2048 + i  (32768 rows)
    const float inv = 1.f / l[row];
    float* rowf = attnbuf + (size_t)row * 2048;
    const us8 ev = *(const us8*)((const u16*)rowf + threadIdx.x * 8);
    __syncthreads();                           // all reads done before any write
    float4 o0, o1;
    o0.x = bf2f(ev[0])*inv; o0.y = bf2f(ev[1])*inv;
    o0.z = bf2f(ev[2])*inv; o0.w = bf2f(ev[3])*inv;
    o1.x = bf2f(ev[4])*inv; o1.y = bf2f(ev[5])*inv;
    o1.z = bf2f(ev[6])*inv; o1.w = bf2f(ev[7])*inv;
    float* dst = rowf + threadIdx.x * 8;
    *(float4*)dst       = o0;
    *(float4*)(dst + 4) = o1;
}

// ============================================================
// O projection: out = o @ Wo^T + bo, 3-term split-bf16 MFMA.
// ============================================================
__global__ __launch_bounds__(256, 2)
void oproj_mfma_kernel(const unsigned char* __restrict__ wsb,
                       const float* __restrict__ Wo, const float* __restrict__ bo,
                       float* __restrict__ out)
{
    const int z = blockIdx.z;
    const u16* Ah_g = (const u16*)(wsb + (z ? OIH_OFF : ORH_OFF));
    const u16* Al_g = (const u16*)(wsb + (z ? OIL_OFF : ORL_OFF));
    float* outp = out + (size_t)z * PE_;

    const int m0 = blockIdx.x * 128;
    const int n0 = blockIdx.y * 64;

    __shared__ __align__(16) unsigned char L[49152];
    enum : u32 { AH=0, AL=16384, BH=32768, BL=40960 };

    const int tid  = threadIdx.x;
    const int lane = tid & 63;
    const int wid  = tid >> 6;
    const int wr   = wid >> 1, wc = wid & 1;
    const int l31  = lane & 31;
    const int hi   = lane >> 5;
    const u32 rowA0 = (u32)(wr*64 + l31);
    const u32 rowB  = (u32)(wc*32 + l31);

    f32x16 c0, c1;
    #pragma unroll
    for (int r = 0; r < 16; ++r) { c0[r] = 0.f; c1[r] = 0.f; }

    const int ch = tid & 7, r0 = tid >> 3;

    for (int k0 = 0; k0 < 512; k0 += 64) {
        __syncthreads();
        #pragma unroll
        for (int rr = 0; rr < 4; ++rr) {
            u32 row = (u32)(rr*32 + r0);
            u32 dst = row*128u + (((u32)ch<<4) ^ ((row&7u)<<4));
            us8 vh = *(const us8*)(Ah_g + (size_t)(m0 + row)*512 + k0 + ch*8);
            us8 vl = *(const us8*)(Al_g + (size_t)(m0 + row)*512 + k0 + ch*8);
            *(us8*)(L + AH + dst) = vh;
            *(us8*)(L + AL + dst) = vl;
        }
        #pragma unroll
        for (int rr = 0; rr < 2; ++rr) {
            u32 row = (u32)(rr*32 + r0);
            const float* src = Wo + (size_t)(n0 + row)*512 + k0 + ch*8;
            float4 v0 = *(const float4*)src;
            float4 v1 = *(const float4*)(src + 4);
            float vv[8] = { v0.x,v0.y,v0.z,v0.w, v1.x,v1.y,v1.z,v1.w };
            us8 hv, lv;
            #pragma unroll
            for (int j = 0; j < 8; ++j) {
                u16 hb = f2bf(vv[j]);
                hv[j] = hb;
                lv[j] = f2bf(vv[j] - bf2f(hb));
            }
            u32 dst = row*128u + (((u32)ch<<4) ^ ((row&7u)<<4));
            *(us8*)(L + BH + dst) = hv;
            *(us8*)(L + BL + dst) = lv;
        }
        __syncthreads();

        #pragma unroll
        for (int ks = 0; ks < 4; ++ks) {
            u32 colb = (u32)(ks*32 + hi*16);
            s8v a0h = ldfrag(L, AH, rowA0,      colb);
            s8v a1h = ldfrag(L, AH, rowA0 + 32, colb);
            s8v a0l = ldfrag(L, AL, rowA0,      colb);
            s8v a1l = ldfrag(L, AL, rowA0 + 32, colb);
            s8v bh_ = ldfrag(L, BH, rowB,       colb);
            s8v bl_ = ldfrag(L, BL, rowB,       colb);
            c0 = MFMA32(a0h, bh_, c0); c0 = MFMA32(a0h, bl_, c0); c0 = MFMA32(a0l, bh_, c0);
            c1 = MFMA32(a1h, bh_, c1); c1 = MFMA32(a1h, bl_, c1); c1 = MFMA32(a1l, bh_, c1);
        }
    }

    const int n = n0 + wc*32 + l31;
    const float bvv = bo[n];
    #pragma unroll
    for (int f = 0; f < 2; ++f) {
        const f32x16& c = f ? c1 : c0;
        #pragma unroll
        for (int r = 0; r < 16; ++r) {
            int m = m0 + wr*64 + 32*f + ROWOF(r, hi);
            outp[(size_t)m*512 + n] = c[r] + bvv;
        }
    }
}

// ============================================================
extern "C" void kernel_launch(void* const* d_in, const int* in_sizes, int n_in,
                              void* d_out, int out_size, void* d_ws, size_t ws_size,
                              hipStream_t stream)
{
    const float* wave_real = (const float*)d_in[0];
    const float* wave_imag = (const float*)d_in[1];
    const float* Wq = (const float*)d_in[2]; const float* bq = (const float*)d_in[3];
    const float* Wk = (const float*)d_in[4]; const float* bk = (const float*)d_in[5];
    const float* Wv = (const float*)d_in[6]; const float* bv = (const float*)d_in[7];
    const float* Wo = (const float*)d_in[8]; const float* bo = (const float*)d_in[9];
    float* out = (float*)d_out;
    unsigned char* outb = (unsigned char*)d_out;
    unsigned char* wsb  = (unsigned char*)d_ws;

    float* attnbuf = out + 2*PE_;

    split_prep_kernel<<<dim3(2048, 2), dim3(256), 0, stream>>>(wave_real, wave_imag, outb);

    wsplit_prep_kernel<<<dim3(64, 3), dim3(256), 0, stream>>>(Wq, Wk, Wv, outb);

    proj_mfma_kernel<<<dim3(32, 8, 6), dim3(256), 0, stream>>>(
        outb, bq, bk, bv,
        (u16*)wsb, (u16*)(wsb + VT_OFF));

    qkmax_kernel<<<dim3(1024), dim3(256), 0, stream>>>(
        (const u16*)wsb, (float*)(wsb + MX0_OFF), (float*)(wsb + MX1_OFF));

    attn_mfma_kernel<<<dim3(512), dim3(256), 0, stream>>>(
        (const u16*)wsb, (const u16*)(wsb + VT_OFF), attnbuf,
        (u16*)(wsb + ORH_OFF), (u16*)(wsb + ORL_OFF),
        (u16*)(wsb + OIH_OFF), (u16*)(wsb + OIL_OFF),
        (float*)(wsb + LV_OFF),
        (const float*)(wsb + MX0_OFF), (const float*)(wsb + MX1_OFF));

    expand_attn_kernel<<<dim3(32768), dim3(256), 0, stream>>>(
        attnbuf, (const float*)(wsb + LV_OFF));

    oproj_mfma_kernel<<<dim3(32, 8, 2), dim3(256), 0, stream>>>(
        wsb, Wo, bo, out);
}

// Round 24
// 329.078 us; speedup vs baseline: 1.0424x; 1.0424x over previous
//
#include <hip/hip_runtime.h>

typedef unsigned short u16;
typedef unsigned int   u32;
typedef __attribute__((ext_vector_type(4)))  u16   us4;
typedef __attribute__((ext_vector_type(8)))  u16   us8;
typedef __attribute__((ext_vector_type(8)))  short s8v;
typedef __attribute__((ext_vector_type(16))) float f32x16;

#define L_   2048
#define D_   512
#define H_   8
#define PE_  2097152ull      // B*L*D elements of one fp32 projection array

// ---- ws layout (bytes) ----
#define MATE    2097152ull   // u16 elems per mat
#define BHE     131072u      // u16 elems per (bh) slice of a mat (2048*64)
#define VT_OFF  33554432ull
#define ORH_OFF 41943040ull
#define ORL_OFF 46137344ull
#define OIH_OFF 50331648ull
#define OIL_OFF 54525952ull
#define LV_OFF  58720256ull

// ---- d_out scratch (bytes from out base; inside attnbuf, dead before attn writes) ----
#define XRH_O 16777216ull
#define XRL_O 20971520ull
#define XIH_O 25165824ull
#define XIL_O 29360128ull
#define WSP_O 33554432ull    // W splits: 3 x (hi 512KB + lo 512KB), tile-major pre-swizzled

#define MFMA32(a,b,c) __builtin_amdgcn_mfma_f32_32x32x16_bf16(a,b,c,0,0,0)
#define ROWOF(r,hi) (((r)&3) + 8*((r)>>2) + 4*(hi))

__device__ __forceinline__ u16 f2bf(float x){
    u32 u = __float_as_uint(x);
    u += 0x7FFFu + ((u>>16)&1u);
    return (u16)(u>>16);
}
__device__ __forceinline__ float bf2f(u16 h){ return __uint_as_float(((u32)h)<<16); }

// async 16B/lane global->LDS copy (LDS dest = wave-uniform base + lane*16)
__device__ __forceinline__ void glds16(const void* gsrc, void* ldst)
{
    __builtin_amdgcn_global_load_lds(
        (const __attribute__((address_space(1))) u32*)(unsigned long long)gsrc,
        (__attribute__((address_space(3))) u32*)(u32)(unsigned long long)ldst,
        16, 0, 0);
}
// one 8KB qk-mat (64 rows x 128B contiguous, pre-swizzled): 8 x 1KB issues
__device__ __forceinline__ void glds_mat(unsigned char* Lp, u32 matOff,
                                         const u16* g, int rowBase, int lane)
{
    const char* gb = (const char*)(g + (size_t)rowBase * 64);
    #pragma unroll
    for (int s = 0; s < 8; ++s)
        glds16(gb + s*1024 + lane*16, Lp + matOff + s*1024);
}
// half a V^T mat (4 x 1KB segments; rows strided 4096B, pre-swizzled per 128B block)
__device__ __forceinline__ void glds_vt(unsigned char* Lp, u32 matOff,
                                        const u16* g, int j0, int lane, int s0)
{
    #pragma unroll
    for (int s = 0; s < 4; ++s) {
        int seg = s0 + s;
        int dh  = seg*8 + (lane >> 3);
        const char* gp = (const char*)g + (size_t)dh*4096 + (size_t)j0*2 + (lane & 7)*16;
        glds16(gp, Lp + matOff + seg*1024u);
    }
}

// ============================================================
// Prep: split wave_real / wave_imag into bf16 hi/lo mats (d_out scratch)
// ============================================================
__global__ __launch_bounds__(256)
void split_prep_kernel(const float* __restrict__ wr, const float* __restrict__ wi,
                       unsigned char* __restrict__ outb)
{
    const int z = blockIdx.y;
    const float* src = z ? wi : wr;
    u16* hg = (u16*)(outb + (z ? XIH_O : XRH_O));
    u16* lg = (u16*)(outb + (z ? XIL_O : XRL_O));
    const size_t idx4 = ((size_t)blockIdx.x * 256 + threadIdx.x) * 4;
    float4 v = *(const float4*)&src[idx4];
    float vv[4] = { v.x, v.y, v.z, v.w };
    us4 h, l;
    #pragma unroll
    for (int c = 0; c < 4; ++c) {
        u16 hb = f2bf(vv[c]);
        h[c] = hb;
        l[c] = f2bf(vv[c] - bf2f(hb));
    }
    *(us4*)&hg[idx4] = h;
    *(us4*)&lg[idx4] = l;
}

// ============================================================
// Prep: split Wq/Wk/Wv into PRE-SWIZZLED tile-major bf16 hi/lo.
// ============================================================
__global__ __launch_bounds__(256)
void wsplit_prep_kernel(const float* __restrict__ Wq, const float* __restrict__ Wk,
                        const float* __restrict__ Wv, unsigned char* __restrict__ outb)
{
    const int tileid = blockIdx.x;          // nb*8 + kb
    const int z = blockIdx.y;               // 0 Wq, 1 Wk, 2 Wv
    const float* W = (z == 0) ? Wq : (z == 1) ? Wk : Wv;
    u16* hg = (u16*)(outb + WSP_O + (size_t)z*1048576ull) + (size_t)tileid*4096;
    u16* lg = hg + 262144;                  // +512KB
    const int nb = tileid >> 3, kb = tileid & 7;
    const int t  = threadIdx.x;
    const int r  = t >> 2;
    const int c0 = (t & 3) * 16;
    const float* src = W + (size_t)(nb*64 + r)*512 + kb*64 + c0;
    #pragma unroll
    for (int j = 0; j < 2; ++j) {
        us8 hv, lv;
        #pragma unroll
        for (int e = 0; e < 8; ++e) {
            float v = src[j*8 + e];
            u16 hb = f2bf(v);
            hv[e] = hb;
            lv[e] = f2bf(v - bf2f(hb));
        }
        int dst = r*64 + ((c0 + j*8) ^ ((r & 7) << 3));
        *(us8*)(hg + dst) = hv;
        *(us8*)(lg + dst) = lv;
    }
}

// ============================================================
// LDS fragment read (XOR swizzle byte ^= (row&7)<<4)
// ============================================================
__device__ __forceinline__ s8v ldfrag(const unsigned char* Lp, u32 matOff, u32 row, u32 colb)
{
    return *(const s8v*)(Lp + matOff + row*128u + (colb ^ ((row&7u)<<4)));
}

// ============================================================
// MFMA projection: C = X @ W^T + b for 6 combos. (R19, unchanged)
// ============================================================
__global__ __launch_bounds__(256, 2)
void proj_mfma_kernel(const unsigned char* __restrict__ scr,
                      const float* __restrict__ bq, const float* __restrict__ bk,
                      const float* __restrict__ bv,
                      u16* __restrict__ qk, u16* __restrict__ vt)
{
    const int z = blockIdx.z;
    const u16* Ah_g = (const u16*)(scr + ((z & 1) ? XIH_O : XRH_O));
    const u16* Al_g = (const u16*)(scr + ((z & 1) ? XIL_O : XRL_O));
    const int wsel = z >> 1;
    const float* bias = (wsel == 0) ? bq : (wsel == 1) ? bk : bv;
    const bool four = (wsel < 2);

    const u16* wh = (const u16*)(scr + WSP_O + (size_t)wsel*1048576ull);
    const u16* wl = wh + 262144;

    const int m0 = blockIdx.x * 128;
    const int n0 = blockIdx.y * 64;
    const int nb = blockIdx.y;

    __shared__ __align__(16) unsigned char L[49152];
    enum : u32 { AH=0, AL=16384, BH=32768, BL=40960 };

    const int tid  = threadIdx.x;
    const int lane = tid & 63;
    const int wid  = tid >> 6;
    const int wr   = wid >> 1, wc = wid & 1;
    const int l31  = lane & 31;
    const int hi   = lane >> 5;
    const u32 rowA0 = (u32)(wr*64 + l31);
    const u32 rowB  = (u32)(wc*32 + l31);

    f32x16 c0, c1;
    #pragma unroll
    for (int r = 0; r < 16; ++r) { c0[r] = 0.f; c1[r] = 0.f; }

    const int ch = tid & 7, r0 = tid >> 3;

    for (int k0 = 0; k0 < 512; k0 += 64) {
        __syncthreads();
        {
            const int kb = k0 >> 6;
            const size_t toff = (size_t)(nb*8 + kb)*4096;
            if (wid == 0)              glds_mat(L, BH, wh + toff, 0, lane);
            else if (wid == 1 && four) glds_mat(L, BL, wl + toff, 0, lane);
        }
        #pragma unroll
        for (int rr = 0; rr < 4; ++rr) {
            u32 row = (u32)(rr*32 + r0);
            u32 dst = row*128u + (((u32)ch<<4) ^ ((row&7u)<<4));
            us8 vh = *(const us8*)(Ah_g + (size_t)(m0 + row)*512 + k0 + ch*8);
            *(us8*)(L + AH + dst) = vh;
            if (four) {
                us8 vl = *(const us8*)(Al_g + (size_t)(m0 + row)*512 + k0 + ch*8);
                *(us8*)(L + AL + dst) = vl;
            }
        }
        __syncthreads();

        #pragma unroll
        for (int ks = 0; ks < 4; ++ks) {
            u32 colb = (u32)(ks*32 + hi*16);
            s8v a0h = ldfrag(L, AH, rowA0,      colb);
            s8v a1h = ldfrag(L, AH, rowA0 + 32, colb);
            s8v bh_ = ldfrag(L, BH, rowB,       colb);
            c0 = MFMA32(a0h, bh_, c0);
            c1 = MFMA32(a1h, bh_, c1);
            if (four) {
                s8v a0l = ldfrag(L, AL, rowA0,      colb);
                s8v a1l = ldfrag(L, AL, rowA0 + 32, colb);
                s8v bl_ = ldfrag(L, BL, rowB,       colb);
                c0 = MFMA32(a0h, bl_, c0); c0 = MFMA32(a0l, bh_, c0); c0 = MFMA32(a0l, bl_, c0);
                c1 = MFMA32(a1h, bl_, c1); c1 = MFMA32(a1l, bh_, c1); c1 = MFMA32(a1l, bl_, c1);
            }
        }
    }

    const int n  = n0 + wc*32 + l31;
    const float bvv = bias[n];
    const int h  = n >> 6, dh = n & 63;

    if (z < 4) {
        u16* hg = qk + (size_t)(2*z)   * MATE;
        u16* lg = qk + (size_t)(2*z+1) * MATE;
        #pragma unroll
        for (int f = 0; f < 2; ++f) {
            const f32x16& c = f ? c1 : c0;
            #pragma unroll
            for (int r = 0; r < 16; ++r) {
                int m  = m0 + wr*64 + 32*f + ROWOF(r, hi);
                int b_ = m >> 11, i = m & 2047;
                size_t idx = (size_t)(b_*8 + h)*BHE + (size_t)i*64 + (dh ^ ((i&7)<<3));
                float v = c[r] + bvv;
                u16 hb = f2bf(v);
                hg[idx] = hb;
                lg[idx] = f2bf(v - bf2f(hb));
            }
        }
    } else {
        u16* vg = vt + (size_t)(z & 1) * MATE;
        #pragma unroll
        for (int f = 0; f < 2; ++f) {
            const f32x16& c = f ? c1 : c0;
            #pragma unroll
            for (int g = 0; g < 4; ++g) {
                int mb = m0 + wr*64 + 32*f + 8*g + 4*hi;
                int b_ = mb >> 11, ib = mb & 2047;
                us4 pv;
                #pragma unroll
                for (int j = 0; j < 4; ++j) pv[j] = f2bf(c[4*g + j] + bvv);
                int ibs = ib ^ ((dh & 7) << 3);
                *(us4*)&vg[(size_t)(b_*8 + h)*BHE + (size_t)dh*2048 + ibs] = pv;
            }
        }
    }
}

// ============================================================
// MFMA attention — champion: Q-hi resident, Q-lo in regs, full hi*hi
// sweep-1 (2 tiles/barrier-pair), sweep-2 4 barriers/jt with V/P
// overlay, bf16 e to attn row first-half, XCD-chunked grid.
// ============================================================
__global__ __launch_bounds__(256, 2)
void attn_mfma_kernel(const u16* __restrict__ qk,
                      const u16* __restrict__ vt,
                      float* __restrict__ attnbuf,
                      u16* __restrict__ orh, u16* __restrict__ orl,
                      u16* __restrict__ oih, u16* __restrict__ oil,
                      float* __restrict__ l_out)
{
    const int bid = blockIdx.x;
    const int xcd = bid & 7;
    const int seq = bid >> 3;
    const int bh  = xcd*2 + (seq >> 5);
    const int i0  = (seq & 31) * 64;
    const int tid  = threadIdx.x;
    const int lane = tid & 63;
    const int wid  = tid >> 6;
    const int wr   = wid >> 1, wc = wid & 1;
    const int l31  = lane & 31;
    const int hi   = lane >> 5;
    const u32 rowA = wr*32 + l31;
    const u32 rowB = wc*32 + l31;

    __shared__ __align__(16) unsigned char L[49152];
    enum : u32 { QRH=0, QIH=8192,
                 KRH=16384, KRL=24576, KIH=32768, KIL=40960,
                 VRo=16384, VIo=24576,          // overlay KRH,KRL
                 PAC=32768, PAS=40960 };        // overlay KIH,KIL
    float* sc = (float*)(L + PAC);

    const u16* qrh = qk + 0*MATE + (size_t)bh*BHE;
    const u16* qrl = qk + 1*MATE + (size_t)bh*BHE;
    const u16* qih = qk + 2*MATE + (size_t)bh*BHE;
    const u16* qil = qk + 3*MATE + (size_t)bh*BHE;
    const u16* krh = qk + 4*MATE + (size_t)bh*BHE;
    const u16* krl = qk + 5*MATE + (size_t)bh*BHE;
    const u16* kih = qk + 6*MATE + (size_t)bh*BHE;
    const u16* kil = qk + 7*MATE + (size_t)bh*BHE;
    const u16* vtr = vt + 0*MATE + (size_t)bh*BHE;
    const u16* vti = vt + 1*MATE + (size_t)bh*BHE;

    // ---- prologue: wave w stages one Q mat; lo mats land in K temp slots ----
    {
        const u16* qsrc = (wid == 0) ? qrh : (wid == 1) ? qih : (wid == 2) ? qrl : qil;
        const u32  qdst = (wid == 0) ? QRH : (wid == 1) ? QIH : (wid == 2) ? KRH : KRL;
        glds_mat(L, qdst, qsrc, i0, lane);
    }
    __syncthreads();
    // lift Q-lo fragments to registers (32 VGPR)
    s8v qfl[2][4];
    #pragma unroll
    for (int ks = 0; ks < 4; ++ks) {
        u32 colb = (u32)(ks*32 + hi*16);
        qfl[0][ks] = ldfrag(L, KRH, rowA, colb);   // QRL
        qfl[1][ks] = ldfrag(L, KRL, rowA, colb);   // QIL
    }

    // ---------------- sweep 1: row max (hi*hi only, all 32 tiles) ----------------
    float mxv[16];
    #pragma unroll
    for (int r = 0; r < 16; ++r) mxv[r] = 0.f;

    const u16* s1src = (wid & 1) ? kih : krh;
    const u32  s1off = 16384u + (u32)wid * 8192u;

    for (int jp = 0; jp < 16; ++jp) {
        __syncthreads();                       // prev reads done (fences qfl lift at jp=0)
        glds_mat(L, s1off, s1src, (2*jp + (wid >> 1))*64, lane);
        __syncthreads();                       // K visible (vmcnt drained)
        __builtin_amdgcn_s_setprio(1);
        #pragma unroll
        for (int half = 0; half < 2; ++half) {
            const u32 kR = half ? KIH : KRH;
            const u32 kI = half ? KIL : KRL;
            f32x16 ir, ip, in_;
            #pragma unroll
            for (int r = 0; r < 16; ++r) { ir[r]=0.f; ip[r]=0.f; in_[r]=0.f; }
            #pragma unroll
            for (int ks = 0; ks < 4; ++ks) {
                u32 colb = ks*32 + hi*16;
                s8v aR = ldfrag(L, QRH, rowA, colb);
                s8v aI = ldfrag(L, QIH, rowA, colb);
                s8v bR = ldfrag(L, kR,  rowB, colb);
                s8v bI = ldfrag(L, kI,  rowB, colb);
                ir  = MFMA32(aR, bR, ir);
                ir  = MFMA32(aI, bI, ir);
                ip  = MFMA32(aR, bI, ip);
                in_ = MFMA32(aI, bR, in_);
            }
            #pragma unroll
            for (int r = 0; r < 16; ++r) {
                float xr = ir[r], xi = ip[r] - in_[r];
                float q = xr*xr + xi*xi;
                mxv[r] = fmaxf(mxv[r], q * 0.125f);
            }
        }
        __builtin_amdgcn_s_setprio(0);
    }
    #pragma unroll
    for (int m = 1; m < 32; m <<= 1)
        #pragma unroll
        for (int r = 0; r < 16; ++r) mxv[r] = fmaxf(mxv[r], __shfl_xor(mxv[r], m));

    // cross-wave (wc) combine via scratch in P region
    __syncthreads();
    #pragma unroll
    for (int r = 0; r < 16; ++r)
        if (l31 == r) sc[wc*64 + wr*32 + ROWOF(r,hi)] = mxv[r];
    __syncthreads();
    float mfin[16];
    #pragma unroll
    for (int r = 0; r < 16; ++r) {
        u32 row = wr*32 + ROWOF(r,hi);
        mfin[r] = fmaxf(sc[row], sc[64 + row]);
    }

    // ---------------- sweep 2 (4 barriers/jt, V/P overlay K) ----------------
    f32x16 ore, oim;
    float lp[16];
    #pragma unroll
    for (int r = 0; r < 16; ++r) { ore[r]=0.f; oim[r]=0.f; lp[r]=0.f; }

    const u16* s2src = (wid == 0) ? krh : (wid == 1) ? krl : (wid == 2) ? kih : kil;
    const u32  s2off = 16384u + (u32)wid * 8192u;
    const u16* vsrc  = (wid < 2) ? vtr : vti;
    const u32  voff  = (wid < 2) ? VRo : VIo;
    const int  vseg  = (wid & 1) * 4;

    // bf16 e destination: first half (4KB) of each 8KB attention row
    u16* ebase = (u16*)(attnbuf + (size_t)bh*4194304ull + (size_t)i0*2048);

    for (int jt = 0; jt < 32; ++jt) {
        const int j0 = jt * 64;
        __syncthreads();                       // #1: PV(jt-1) done; K region free
        glds_mat(L, s2off, s2src, j0, lane);   // wave w -> K mat w
        __syncthreads();                       // #2: K staged (vmcnt drained)

        f32x16 ir, ip, in_;
        #pragma unroll
        for (int r = 0; r < 16; ++r) { ir[r]=0.f; ip[r]=0.f; in_[r]=0.f; }
        __builtin_amdgcn_s_setprio(1);
        #pragma unroll
        for (int ks = 0; ks < 4; ++ks) {
            u32 colb = ks*32 + hi*16;
            s8v aRH = ldfrag(L, QRH, rowA, colb);
            s8v aIH = ldfrag(L, QIH, rowA, colb);
            s8v aRL = qfl[0][ks];
            s8v aIL = qfl[1][ks];
            s8v bRH = ldfrag(L, KRH, rowB, colb);
            s8v bRL = ldfrag(L, KRL, rowB, colb);
            s8v bIH = ldfrag(L, KIH, rowB, colb);
            s8v bIL = ldfrag(L, KIL, rowB, colb);
            ir = MFMA32(aRH, bRH, ir); ir = MFMA32(aRH, bRL, ir); ir = MFMA32(aRL, bRH, ir);
            ir = MFMA32(aIH, bIH, ir); ir = MFMA32(aIH, bIL, ir); ir = MFMA32(aIL, bIH, ir);
            ip  = MFMA32(aRH, bIH, ip);  ip  = MFMA32(aRH, bIL, ip);  ip  = MFMA32(aRL, bIH, ip);
            in_ = MFMA32(aIH, bRH, in_); in_ = MFMA32(aIH, bRL, in_); in_ = MFMA32(aIL, bRH, in_);
        }
        __builtin_amdgcn_s_setprio(0);
        __syncthreads();                       // #3: K reads done -> V/P may overwrite

        glds_vt(L, voff, vsrc, j0, lane, vseg);   // async V; lands under pointwise

        // pointwise: e (bf16) -> attn row first-half; P -> LDS (hides V loads)
        #pragma unroll
        for (int r = 0; r < 16; ++r) {
            float xr = ir[r], xi = ip[r] - in_[r];
            float q  = fmaf(xr, xr, xi*xi);
            float e  = __expf(fmaf(q, 0.125f, -mfin[r]));
            lp[r] += e;
            float iv = rsqrtf(q);
            float t  = e * iv;
            float pc = (q > 0.f) ? xr*t : e;
            float ps = (q > 0.f) ? xi*t : 0.0f;
            u32 rowloc = wr*32 + ROWOF(r,hi);
            ebase[(size_t)rowloc*4096 + j0 + wc*32 + l31] = f2bf(e);
            u32 colb2 = (wc*32 + l31)*2;
            *(u16*)(L + PAC + rowloc*128u + (colb2 ^ ((rowloc&7u)<<4))) = f2bf(pc);
            *(u16*)(L + PAS + rowloc*128u + (colb2 ^ ((rowloc&7u)<<4))) = f2bf(ps);
        }
        __syncthreads();                       // #4: V (vmcnt) + P visible

        __builtin_amdgcn_s_setprio(1);
        #pragma unroll
        for (int ks = 0; ks < 4; ++ks) {
            u32 colb = ks*32 + hi*16;
            s8v aC = ldfrag(L, PAC, rowA, colb);
            s8v aS = ldfrag(L, PAS, rowA, colb);
            s8v vR = ldfrag(L, VRo, rowB, colb);
            s8v vI = ldfrag(L, VIo, rowB, colb);
            s8v vN = vI ^ (short)0x8000;       // -Vi (register sign-flip)
            ore = MFMA32(aC, vR, ore); ore = MFMA32(aS, vN, ore);
            oim = MFMA32(aS, vR, oim); oim = MFMA32(aC, vI, oim);
        }
        __builtin_amdgcn_s_setprio(0);
    }

    // ---------------- epilogue: l, normalize O, store splits ----------------
    #pragma unroll
    for (int m = 1; m < 32; m <<= 1)
        #pragma unroll
        for (int r = 0; r < 16; ++r) lp[r] += __shfl_xor(lp[r], m);

    __syncthreads();                           // last PV done -> reuse PAC scratch
    #pragma unroll
    for (int r = 0; r < 16; ++r)
        if (l31 == r) sc[wc*64 + wr*32 + ROWOF(r,hi)] = lp[r];
    __syncthreads();

    const int b_ = bh >> 3, h = bh & 7;
    const size_t cb = (size_t)h*64 + wc*32 + l31;
    #pragma unroll
    for (int r = 0; r < 16; ++r) {
        u32 row = wr*32 + ROWOF(r,hi);
        float ls = sc[row] + sc[64 + row];
        if (wc == 0 && l31 == 0) l_out[(size_t)bh*2048 + i0 + row] = ls;
        float inv = 1.0f / ls;
        size_t idx = ((size_t)b_*2048 + i0 + row)*512 + cb;
        float vr = ore[r] * inv;
        float vi = oim[r] * inv;
        u16 hr = f2bf(vr); orh[idx] = hr; orl[idx] = f2bf(vr - bf2f(hr));
        u16 hw = f2bf(vi); oih[idx] = hw; oil[idx] = f2bf(vi - bf2f(hw));
    }
}

// ============================================================
// Expand: one block per attention row. Read the row's bf16 e (first
// 4KB, into registers), sync, write the full fp32 row = e / l[row].
// ============================================================
__global__ __launch_bounds__(256)
void expand_attn_kernel(float* __restrict__ attnbuf, const float* __restrict__ l)
{
    const int row = blockIdx.x;                // bh*2048 + i  (32768 rows)
    const float inv = 1.f / l[row];
    float* rowf = attnbuf + (size_t)row * 2048;
    const us8 ev = *(const us8*)((const u16*)rowf + threadIdx.x * 8);
    __syncthreads();                           // all reads done before any write
    float4 o0, o1;
    o0.x = bf2f(ev[0])*inv; o0.y = bf2f(ev[1])*inv;
    o0.z = bf2f(ev[2])*inv; o0.w = bf2f(ev[3])*inv;
    o1.x = bf2f(ev[4])*inv; o1.y = bf2f(ev[5])*inv;
    o1.z = bf2f(ev[6])*inv; o1.w = bf2f(ev[7])*inv;
    float* dst = rowf + threadIdx.x * 8;
    *(float4*)dst       = o0;
    *(float4*)(dst + 4) = o1;
}

// ============================================================
// O projection: out = o @ Wo^T + bo, 3-term split-bf16 MFMA.
// ============================================================
__global__ __launch_bounds__(256, 2)
void oproj_mfma_kernel(const unsigned char* __restrict__ wsb,
                       const float* __restrict__ Wo, const float* __restrict__ bo,
                       float* __restrict__ out)
{
    const int z = blockIdx.z;
    const u16* Ah_g = (const u16*)(wsb + (z ? OIH_OFF : ORH_OFF));
    const u16* Al_g = (const u16*)(wsb + (z ? OIL_OFF : ORL_OFF));
    float* outp = out + (size_t)z * PE_;

    const int m0 = blockIdx.x * 128;
    const int n0 = blockIdx.y * 64;

    __shared__ __align__(16) unsigned char L[49152];
    enum : u32 { AH=0, AL=16384, BH=32768, BL=40960 };

    const int tid  = threadIdx.x;
    const int lane = tid & 63;
    const int wid  = tid >> 6;
    const int wr   = wid >> 1, wc = wid & 1;
    const int l31  = lane & 31;
    const int hi   = lane >> 5;
    const u32 rowA0 = (u32)(wr*64 + l31);
    const u32 rowB  = (u32)(wc*32 + l31);

    f32x16 c0, c1;
    #pragma unroll
    for (int r = 0; r < 16; ++r) { c0[r] = 0.f; c1[r] = 0.f; }

    const int ch = tid & 7, r0 = tid >> 3;

    for (int k0 = 0; k0 < 512; k0 += 64) {
        __syncthreads();
        #pragma unroll
        for (int rr = 0; rr < 4; ++rr) {
            u32 row = (u32)(rr*32 + r0);
            u32 dst = row*128u + (((u32)ch<<4) ^ ((row&7u)<<4));
            us8 vh = *(const us8*)(Ah_g + (size_t)(m0 + row)*512 + k0 + ch*8);
            us8 vl = *(const us8*)(Al_g + (size_t)(m0 + row)*512 + k0 + ch*8);
            *(us8*)(L + AH + dst) = vh;
            *(us8*)(L + AL + dst) = vl;
        }
        #pragma unroll
        for (int rr = 0; rr < 2; ++rr) {
            u32 row = (u32)(rr*32 + r0);
            const float* src = Wo + (size_t)(n0 + row)*512 + k0 + ch*8;
            float4 v0 = *(const float4*)src;
            float4 v1 = *(const float4*)(src + 4);
            float vv[8] = { v0.x,v0.y,v0.z,v0.w, v1.x,v1.y,v1.z,v1.w };
            us8 hv, lv;
            #pragma unroll
            for (int j = 0; j < 8; ++j) {
                u16 hb = f2bf(vv[j]);
                hv[j] = hb;
                lv[j] = f2bf(vv[j] - bf2f(hb));
            }
            u32 dst = row*128u + (((u32)ch<<4) ^ ((row&7u)<<4));
            *(us8*)(L + BH + dst) = hv;
            *(us8*)(L + BL + dst) = lv;
        }
        __syncthreads();

        #pragma unroll
        for (int ks = 0; ks < 4; ++ks) {
            u32 colb = (u32)(ks*32 + hi*16);
            s8v a0h = ldfrag(L, AH, rowA0,      colb);
            s8v a1h = ldfrag(L, AH, rowA0 + 32, colb);
            s8v a0l = ldfrag(L, AL, rowA0,      colb);
            s8v a1l = ldfrag(L, AL, rowA0 + 32, colb);
            s8v bh_ = ldfrag(L, BH, rowB,       colb);
            s8v bl_ = ldfrag(L, BL, rowB,       colb);
            c0 = MFMA32(a0h, bh_, c0); c0 = MFMA32(a0h, bl_, c0); c0 = MFMA32(a0l, bh_, c0);
            c1 = MFMA32(a1h, bh_, c1); c1 = MFMA32(a1h, bl_, c1); c1 = MFMA32(a1l, bh_, c1);
        }
    }

    const int n = n0 + wc*32 + l31;
    const float bvv = bo[n];
    #pragma unroll
    for (int f = 0; f < 2; ++f) {
        const f32x16& c = f ? c1 : c0;
        #pragma unroll
        for (int r = 0; r < 16; ++r) {
            int m = m0 + wr*64 + 32*f + ROWOF(r, hi);
            outp[(size_t)m*512 + n] = c[r] + bvv;
        }
    }
}

// ============================================================
extern "C" void kernel_launch(void* const* d_in, const int* in_sizes, int n_in,
                              void* d_out, int out_size, void* d_ws, size_t ws_size,
                              hipStream_t stream)
{
    const float* wave_real = (const float*)d_in[0];
    const float* wave_imag = (const float*)d_in[1];
    const float* Wq = (const float*)d_in[2]; const float* bq = (const float*)d_in[3];
    const float* Wk = (const float*)d_in[4]; const float* bk = (const float*)d_in[5];
    const float* Wv = (const float*)d_in[6]; const float* bv = (const float*)d_in[7];
    const float* Wo = (const float*)d_in[8]; const float* bo = (const float*)d_in[9];
    float* out = (float*)d_out;
    unsigned char* outb = (unsigned char*)d_out;
    unsigned char* wsb  = (unsigned char*)d_ws;

    float* attnbuf = out + 2*PE_;

    split_prep_kernel<<<dim3(2048, 2), dim3(256), 0, stream>>>(wave_real, wave_imag, outb);

    wsplit_prep_kernel<<<dim3(64, 3), dim3(256), 0, stream>>>(Wq, Wk, Wv, outb);

    proj_mfma_kernel<<<dim3(32, 8, 6), dim3(256), 0, stream>>>(
        outb, bq, bk, bv,
        (u16*)wsb, (u16*)(wsb + VT_OFF));

    attn_mfma_kernel<<<dim3(512), dim3(256), 0, stream>>>(
        (const u16*)wsb, (const u16*)(wsb + VT_OFF), attnbuf,
        (u16*)(wsb + ORH_OFF), (u16*)(wsb + ORL_OFF),
        (u16*)(wsb + OIH_OFF), (u16*)(wsb + OIL_OFF),
        (float*)(wsb + LV_OFF));

    expand_attn_kernel<<<dim3(32768), dim3(256), 0, stream>>>(
        attnbuf, (const float*)(wsb + LV_OFF));

    oproj_mfma_kernel<<<dim3(32, 8, 2), dim3(256), 0, stream>>>(
        wsb, Wo, bo, out);
}